// Round 13
// baseline (206.663 us; speedup 1.0000x reference)
//
#include <hip/hip_runtime.h>
#include <hip/hip_bf16.h>
#include <stdint.h>

// ---------------------------------------------------------------------------
// Attention_47330539602252 on MI355X (gfx950). fp32 I/O, bf16 MFMA compute.
// B=8 N=1024 C=768 H=12 hd=64; quad2: t=(s*0.125+5)^2, row-normalized.
// R23 = R22 (184.9us PASS; FETCH 104.5->19.4MB confirmed XCD-locality) with
// attn restructured for phase-decoupled TLP + conflict-free Pl:
//  (a) 1-WAVE blocks: grid 96x16 (bh fast -> same-XCD kept), 64 threads,
//      each wave owns 64 q-rows (4 subtiles). Same per-wave MFMA/ds_read
//      work as before (R15's failed 4-wave split duplicated frag reads;
//      this does NOT). The 2-wave blocks barrier-locked both waves into
//      stalling together at each stage drain; 6 independent waves/CU have
//      anti-correlated phases -> stage latency masked. No __syncthreads;
//      explicit vmcnt(0) after stage, lgkmcnt(0) before LDS overwrite
//      (same-iteration sequential pattern — the one that always passed).
//  (b) Pl stride 80->88: stride-80 put l16%4-aliased lanes on one bank
//      (4-way conflict, the 4.7M counter); stride 88 (12*l16 mod 32,
//      period 8) -> free 2-way. Alignment: 176B rows keep 8B/16B aligned.
// QKV+proj (gemm_m97<EPI>) and cvt_all byte-identical to R21/R22.
// MFMA layouts (HW-verified):
//   A-frag: A[m=lane&15][k=quad*8+j]   B-frag: B[n=lane&15][k=quad*8+j]
//   C/D:    col(n)=lane&15, row(m)=quad*4+reg
// ---------------------------------------------------------------------------

typedef short  s8v  __attribute__((ext_vector_type(8)));  // 8 bf16 raw bits
typedef float  f4v  __attribute__((ext_vector_type(4)));

__device__ inline uint16_t f2bf(float f) {
    union { float f; uint32_t u; } c; c.f = f;
    uint32_t u = c.u;
    u += 0x7fffu + ((u >> 16) & 1u);   // RNE
    return (uint16_t)(u >> 16);
}
__device__ inline uint32_t pack2bf(float a, float b) {
    union { __hip_bfloat162 v; uint32_t u; } c;
    c.v = __float22bfloat162_rn(float2{a, b});   // x=a -> low 16 bits
    return c.u;
}

// async global->LDS, 16B per lane (LDS dest = wave-uniform base + lane*16)
__device__ inline void cp16(const uint16_t* g, uint16_t* l) {
    __builtin_amdgcn_global_load_lds(
        (const __attribute__((address_space(1))) void*)g,
        (__attribute__((address_space(3))) void*)l, 16, 0, 0);
}

// ---------------------------------------------------------------------------
// fp32 -> bf16 for all three inputs in one launch (dests contiguous in ws).
// ---------------------------------------------------------------------------
__global__ __launch_bounds__(256) void cvt_all(
    const float* __restrict__ x, const float* __restrict__ qw,
    const float* __restrict__ pw, uint16_t* __restrict__ dst)
{
    // totals in 8-elem groups: x 786432 | qkv_w 221184 | proj_w 73728
    int i = blockIdx.x * 256 + threadIdx.x;
    if (i >= 1081344) return;
    const float* s;
    if (i < 786432)       s = x  + (size_t)i * 8;
    else if (i < 1007616) s = qw + ((size_t)i - 786432) * 8;
    else                  s = pw + ((size_t)i - 1007616) * 8;
    const float4* sp = reinterpret_cast<const float4*>(s);
    float4 a = sp[0], b = sp[1];
    s8v o;
    o[0] = (short)f2bf(a.x); o[1] = (short)f2bf(a.y);
    o[2] = (short)f2bf(a.z); o[3] = (short)f2bf(a.w);
    o[4] = (short)f2bf(b.x); o[5] = (short)f2bf(b.y);
    o[6] = (short)f2bf(b.z); o[7] = (short)f2bf(b.w);
    *reinterpret_cast<s8v*>(dst + (size_t)i * 8) = o;
}

// ---------------------------------------------------------------------------
// m97-structure GEMM-BT (byte-identical R21/R22): C = A[M,768] @ Bm[N,768]^T.
// BM=BN=128, BK=64. 4 waves, 32KB swizzled single-buffer LDS, XCD-bijective
// block swizzle. EPI==0: q/k scatter + V packed ushort4. EPI==1: +bias fp32.
// ---------------------------------------------------------------------------
template <int EPI>
__global__ __launch_bounds__(256) void gemm_m97(
    const uint16_t* __restrict__ A, const uint16_t* __restrict__ Bm,
    uint16_t* __restrict__ qb, uint16_t* __restrict__ kb, uint16_t* __restrict__ vb,
    const float* __restrict__ bias, float* __restrict__ Cout, int GN)
{
    constexpr int K  = 768;
    constexpr int NT = K / 64;               // 12 K-steps

    __shared__ uint16_t Al[128 * 64];        // 16 KB
    __shared__ uint16_t Bl[128 * 64];        // 16 KB

    const int tid  = threadIdx.x;
    const int wave = tid >> 6, lane = tid & 63;
    const int quad = lane >> 4, l16 = lane & 15;
    const int wM = wave >> 1, wN = wave & 1;

    // T1: XCD-bijective swizzle (gridDim.x % 8 == 0 for both call sites)
    const int nwg = (int)gridDim.x;
    const int wg  = ((int)blockIdx.x & 7) * (nwg >> 3) + ((int)blockIdx.x >> 3);
    const int bM = wg / GN, bN = wg - bM * GN;

    const uint16_t* Ag = A  + (size_t)bM * 128 * K;
    const uint16_t* Bg = Bm + (size_t)bN * 128 * K;

    f4v acc[4][4];
#pragma unroll
    for (int i = 0; i < 4; i++)
#pragma unroll
        for (int j = 0; j < 4; j++) { f4v z = {0.f, 0.f, 0.f, 0.f}; acc[i][j] = z; }

    for (int t = 0; t < NT; ++t) {
        __syncthreads();
        // chunk ch: row r=ch>>3; phys chunk ch&7 holds logical lc=(ch&7)^(r&7)
#pragma unroll
        for (int u = 0; u < 4; ++u) {
            const int ch = tid + u * 256;
            const int r  = ch >> 3, lc = (ch & 7) ^ (r & 7);
            cp16(Ag + (size_t)r * K + t * 64 + lc * 8, &Al[ch * 8]);
        }
#pragma unroll
        for (int u = 0; u < 4; ++u) {
            const int ch = tid + u * 256;
            const int r  = ch >> 3, lc = (ch & 7) ^ (r & 7);
            cp16(Bg + (size_t)r * K + t * 64 + lc * 8, &Bl[ch * 8]);
        }
        __syncthreads();

        s8v af[4][2], bq[4][2];
#pragma unroll
        for (int x = 0; x < 4; ++x) {
            const int ra = wM * 64 + x * 16 + l16;
            const int rb = wN * 64 + x * 16 + l16;
#pragma unroll
            for (int kk = 0; kk < 2; ++kk) {
                const int pa = (kk * 4 + quad) ^ (ra & 7);
                const int pb = (kk * 4 + quad) ^ (rb & 7);
                af[x][kk] = *reinterpret_cast<const s8v*>(&Al[ra * 64 + pa * 8]);
                bq[x][kk] = *reinterpret_cast<const s8v*>(&Bl[rb * 64 + pb * 8]);
            }
        }
#pragma unroll
        for (int kk = 0; kk < 2; ++kk)
#pragma unroll
            for (int tm = 0; tm < 4; ++tm)
#pragma unroll
                for (int tn = 0; tn < 4; ++tn)
                    acc[tm][tn] = __builtin_amdgcn_mfma_f32_16x16x32_bf16(
                        af[tm][kk], bq[tn][kk], acc[tm][tn], 0, 0, 0);
    }

    // epilogue (identical scatter logic; BN=128)
#pragma unroll
    for (int tm = 0; tm < 4; tm++) {
#pragma unroll
        for (int tn = 0; tn < 4; tn++) {
            const int col = bN * 128 + wN * 64 + tn * 16 + l16;
            if (EPI == 0) {
                const int three = col / 768;          // block-uniform (128 | 768)
                const int rem   = col - three * 768;
                const int h = rem >> 6, d = rem & 63;
                const int n0 = bM * 128 + wM * 64 + tm * 16 + quad * 4;
                const int b = n0 >> 10, n = n0 & 1023;   // n0%4==0: no b crossing
                if (three == 2) {
                    // V: 4 regs = 4 consecutive tokens at fixed vdim -> ushort4
                    ushort4 pk;
                    pk.x = f2bf(acc[tm][tn][0]);
                    pk.y = f2bf(acc[tm][tn][1]);
                    pk.z = f2bf(acc[tm][tn][2]);
                    pk.w = f2bf(acc[tm][tn][3]);
                    *reinterpret_cast<ushort4*>(
                        &vb[((size_t)((b * 12 + h) * 64 + d)) * 1024 + n]) = pk;
                } else {
                    uint16_t* dst = (three == 0) ? qb : kb;
#pragma unroll
                    for (int reg = 0; reg < 4; reg++)
                        dst[((size_t)((b * 12 + h) * 1024 + n + reg)) * 64 + d] =
                            f2bf(acc[tm][tn][reg]);
                }
            } else {
#pragma unroll
                for (int reg = 0; reg < 4; reg++) {
                    const int row = bM * 128 + wM * 64 + tm * 16 + quad * 4 + reg;
                    Cout[(size_t)row * 768 + col] = acc[tm][tn][reg] + bias[col];
                }
            }
        }
    }
}

// ---------------------------------------------------------------------------
// Fused quad2 attention — R23: 1-WAVE blocks, conflict-free Pl.
// Grid: x=96 (b*12+h, fast -> same-bh blocks on one XCD), y=16 (64-row
// q-tile). 64 threads = 1 wave owning 64 q-rows as 4 subtiles. Per m-tile:
// stage K[m][d], V^T[d][m] (16 cp16, swizzled) -> explicit vmcnt(0) ->
// hoisted XOR-swizzled frags -> S^T = K@Q^T -> t=(s/8+5)^2 -> packed b64 P
// writes (stride-88 Pl, 2-way max) -> PV + ones-MFMA rowsum. No barriers;
// lgkmcnt(0)+memory fence before each overwrite (WAR). O = U/rowsum.
// ---------------------------------------------------------------------------
__global__ __launch_bounds__(64) void attn_quad(
    const uint16_t* __restrict__ Q, const uint16_t* __restrict__ K,
    const uint16_t* __restrict__ VT, uint16_t* __restrict__ O)
{
    const int bh = blockIdx.x;      // 0..95  (fast dim: same-bh -> same XCD)
    const int qt = blockIdx.y;      // 0..15  (64-row tile)
    const int b = bh / 12, h = bh - (bh / 12) * 12;
    const uint16_t* Qp = Q  + (size_t)bh * 65536;
    const uint16_t* Kp = K  + (size_t)bh * 65536;
    const uint16_t* Vp = VT + (size_t)bh * 65536;   // [d=64][n=1024]

    const int tid  = threadIdx.x;   // 0..63 (one wave)
    const int quad = tid >> 4, l16 = tid & 15;

    __shared__ uint16_t Kl[64 * 64];     // [key][d], chunk-swizzled (8 KB)
    __shared__ uint16_t Vl[64 * 64];     // [d][m],  chunk-swizzled (8 KB)
    __shared__ uint16_t Pl[16][88];      // [qrow][m], stride 88 (2-way max)

    // Q fragments (one-time, direct global): rows qt*64 + s*16 + l16
    s8v qf[4][2];
#pragma unroll
    for (int s = 0; s < 4; s++) {
        const uint16_t* qp = Qp + (size_t)(qt * 64 + s * 16 + l16) * 64 + quad * 8;
        qf[s][0] = *reinterpret_cast<const s8v*>(qp);
        qf[s][1] = *reinterpret_cast<const s8v*>(qp + 32);
    }

    s8v ones;
#pragma unroll
    for (int i = 0; i < 8; i++) ones[i] = (short)0x3F80;   // bf16 1.0

    f4v U[4][4], U5[4];
#pragma unroll
    for (int s = 0; s < 4; s++) {
        f4v z = {0.f, 0.f, 0.f, 0.f};
        U5[s] = z;
#pragma unroll
        for (int c = 0; c < 4; c++) U[s][c] = z;
    }

    for (int mt = 0; mt < 16; mt++) {
        // WAR fence: previous tile's ds_reads complete before DMA overwrite.
        // ("memory" keeps the cp16 intrinsics from hoisting above it.)
        asm volatile("s_waitcnt lgkmcnt(0)" ::: "memory");
        // stage: 8 K-chunks + 8 V-chunks per thread (512 chunks each tile).
        // swizzle: physical chunk pc of row holds logical pc^(row&7)
#pragma unroll
        for (int r = 0; r < 8; ++r) {
            const int e   = (tid + r * 64) * 8;
            const int row = e >> 6;                       // key for K, d for V
            const int cl  = ((e >> 3) & 7) ^ (row & 7);   // logical chunk fetched
            cp16(Kp + (size_t)mt * 4096 + (size_t)row * 64 + cl * 8, &Kl[e]);
            cp16(Vp + (size_t)row * 1024 + mt * 64 + cl * 8, &Vl[e]);
        }
        // tile resident (single wave: no barrier needed, just the DMA drain;
        // this exposed wait is what co-resident independent waves mask)
        asm volatile("s_waitcnt vmcnt(0)" ::: "memory");

        // hoist K/V fragments (reused by all 4 subtiles); XOR-swizzled reads
        s8v kf[4][2], vf[4][2];
#pragma unroll
        for (int c = 0; c < 4; c++) {
            const int rr = c * 16 + l16;
#pragma unroll
            for (int kk = 0; kk < 2; kk++) {
                const int pc = (kk * 4 + quad) ^ (rr & 7);
                kf[c][kk] = *reinterpret_cast<const s8v*>(&Kl[rr * 64 + (pc << 3)]);
                vf[c][kk] = *reinterpret_cast<const s8v*>(&Vl[rr * 64 + (pc << 3)]);
            }
        }

#pragma unroll
        for (int s = 0; s < 4; s++) {
            // S^T = K @ Q^T : C col=l16=qrow, row=quad*4+reg = m (in cm tile)
            f4v st[4];
#pragma unroll
            for (int cm = 0; cm < 4; cm++) {
                f4v z = {0.f, 0.f, 0.f, 0.f};
                z = __builtin_amdgcn_mfma_f32_16x16x32_bf16(kf[cm][0], qf[s][0], z, 0, 0, 0);
                z = __builtin_amdgcn_mfma_f32_16x16x32_bf16(kf[cm][1], qf[s][1], z, 0, 0, 0);
                st[cm] = z;
            }
            // t = (s*0.125+5)^2 -> packed b64 write: Pl[l16][cm*16+quad*4 ..+3]
#pragma unroll
            for (int cm = 0; cm < 4; cm++) {
                float t0 = st[cm][0] * 0.125f + 5.0f; t0 *= t0;
                float t1 = st[cm][1] * 0.125f + 5.0f; t1 *= t1;
                float t2 = st[cm][2] * 0.125f + 5.0f; t2 *= t2;
                float t3 = st[cm][3] * 0.125f + 5.0f; t3 *= t3;
                uint2 pk; pk.x = pack2bf(t0, t1); pk.y = pack2bf(t2, t3);
                *reinterpret_cast<uint2*>(&Pl[l16][cm * 16 + quad * 4]) = pk;
            }
            // U += P @ V ; rowsum via ones-MFMA (same-wave DS in-order)
#pragma unroll
            for (int kc = 0; kc < 2; kc++) {
                s8v pf = *reinterpret_cast<const s8v*>(&Pl[l16][kc * 32 + quad * 8]);
                U5[s] = __builtin_amdgcn_mfma_f32_16x16x32_bf16(pf, ones, U5[s], 0, 0, 0);
#pragma unroll
                for (int cd = 0; cd < 4; cd++)
                    U[s][cd] = __builtin_amdgcn_mfma_f32_16x16x32_bf16(pf, vf[cd][kc], U[s][cd], 0, 0, 0);
            }
        }
    }

    // epilogue: O[b, n, h*64+d] = U / rowsum (bf16 intermediate for proj GEMM)
#pragma unroll
    for (int s = 0; s < 4; s++) {
        float inv[4];
#pragma unroll
        for (int reg = 0; reg < 4; reg++) inv[reg] = 1.0f / U5[s][reg];
#pragma unroll
        for (int cd = 0; cd < 4; cd++) {
#pragma unroll
            for (int reg = 0; reg < 4; reg++) {
                const int n = qt * 64 + s * 16 + quad * 4 + reg;
                const int d = cd * 16 + l16;
                O[((size_t)(b * 1024 + n)) * 768 + h * 64 + d] = f2bf(U[s][cd][reg] * inv[reg]);
            }
        }
    }
}

// ---------------------------------------------------------------------------
extern "C" void kernel_launch(void* const* d_in, const int* in_sizes, int n_in,
                              void* d_out, int out_size, void* d_ws, size_t ws_size,
                              hipStream_t stream)
{
    const float* x      = (const float*)d_in[0];   // [8,1024,768]
    const float* qkv_w  = (const float*)d_in[1];   // [2304,768]
    const float* proj_w = (const float*)d_in[2];   // [768,768]
    const float* proj_b = (const float*)d_in[3];   // [768]
    float* out = (float*)d_out;                    // [8,1024,768] fp32

    const size_t NEL = (size_t)8 * 1024 * 768;     // 6291456
    uint16_t* xb  = (uint16_t*)d_ws;               // bf16 x
    uint16_t* qwb = xb  + NEL;                     // bf16 qkv_w (1769472)
    uint16_t* pwb = qwb + 1769472;                 // bf16 proj_w (589824)
    uint16_t* qb  = pwb + 589824;                  // bf16 [B,H,N,64]
    uint16_t* kb  = qb  + NEL;                     // bf16 [B,H,N,64]
    uint16_t* vb  = kb  + NEL;                     // bf16 [B,H,64,N] (transposed)
    uint16_t* ao  = vb  + NEL;                     // bf16 attn out [8192,768]

    cvt_all<<<4224, 256, 0, stream>>>(x, qkv_w, proj_w, xb);

    // QKV: [8192,768] @ [2304,768]^T -> q/k scatter + V packed ushort4
    gemm_m97<0><<<1152, 256, 0, stream>>>(xb, qwb, qb, kb, vb, nullptr, nullptr, 18);
    // fused quad2 attention -> ao [8192,768] bf16
    // R23: 1-wave blocks; bh fast (x=96) keeps same-bh on one XCD
    attn_quad<<<dim3(96, 16), 64, 0, stream>>>(qb, kb, vb, ao);
    // proj: [8192,768] @ [768,768]^T + bias -> fp32 out
    gemm_m97<1><<<384, 256, 0, stream>>>(ao, pwb, nullptr, nullptr, nullptr, proj_b, out, 6);
}

// Round 14
// 184.503 us; speedup vs baseline: 1.1201x; 1.1201x over previous
//
#include <hip/hip_runtime.h>
#include <hip/hip_bf16.h>
#include <stdint.h>

// ---------------------------------------------------------------------------
// Attention_47330539602252 on MI355X (gfx950). fp32 I/O, bf16 MFMA compute.
// B=8 N=1024 C=768 H=12 hd=64; quad2: t=(s*0.125+5)^2, row-normalized.
// R24 = R22 (184.9us best) + ONE retained element of R23: Pl stride 80->88
// in the 2-wave attn (stride-80 aliased l16%4 lanes onto one bank = 4-way
// conflict; R23 measured per-wave conflicts halving with stride 88).
// R23's 1-wave restructure REGRESSED (+20us; occupancy fell 12->7.8%) and
// is reverted — every attn staging variant (4-wave, dbuf, 1-wave) has now
// lost to the plain 2-wave sequential structure.
// Components:
//  - QKV+proj: gemm_m97<EPI> byte-identical R21/R22 (XCD-bijective swizzle;
//    the epilogue write placement is what makes downstream fast — R14/R21
//    vs R18/R20 A/B).
//  - attn: R22 2-wave sequential, grid dim3(96,8) (bh fast -> same-bh
//    blocks share one XCD's L2; FETCH 104.5->19.4MB), Pl stride 88.
// MFMA layouts (HW-verified):
//   A-frag: A[m=lane&15][k=quad*8+j]   B-frag: B[n=lane&15][k=quad*8+j]
//   C/D:    col(n)=lane&15, row(m)=quad*4+reg
// ---------------------------------------------------------------------------

typedef short  s8v  __attribute__((ext_vector_type(8)));  // 8 bf16 raw bits
typedef float  f4v  __attribute__((ext_vector_type(4)));

__device__ inline uint16_t f2bf(float f) {
    union { float f; uint32_t u; } c; c.f = f;
    uint32_t u = c.u;
    u += 0x7fffu + ((u >> 16) & 1u);   // RNE
    return (uint16_t)(u >> 16);
}
__device__ inline uint32_t pack2bf(float a, float b) {
    union { __hip_bfloat162 v; uint32_t u; } c;
    c.v = __float22bfloat162_rn(float2{a, b});   // x=a -> low 16 bits
    return c.u;
}

// async global->LDS, 16B per lane (LDS dest = wave-uniform base + lane*16)
__device__ inline void cp16(const uint16_t* g, uint16_t* l) {
    __builtin_amdgcn_global_load_lds(
        (const __attribute__((address_space(1))) void*)g,
        (__attribute__((address_space(3))) void*)l, 16, 0, 0);
}

// ---------------------------------------------------------------------------
// fp32 -> bf16 for all three inputs in one launch (dests contiguous in ws).
// ---------------------------------------------------------------------------
__global__ __launch_bounds__(256) void cvt_all(
    const float* __restrict__ x, const float* __restrict__ qw,
    const float* __restrict__ pw, uint16_t* __restrict__ dst)
{
    // totals in 8-elem groups: x 786432 | qkv_w 221184 | proj_w 73728
    int i = blockIdx.x * 256 + threadIdx.x;
    if (i >= 1081344) return;
    const float* s;
    if (i < 786432)       s = x  + (size_t)i * 8;
    else if (i < 1007616) s = qw + ((size_t)i - 786432) * 8;
    else                  s = pw + ((size_t)i - 1007616) * 8;
    const float4* sp = reinterpret_cast<const float4*>(s);
    float4 a = sp[0], b = sp[1];
    s8v o;
    o[0] = (short)f2bf(a.x); o[1] = (short)f2bf(a.y);
    o[2] = (short)f2bf(a.z); o[3] = (short)f2bf(a.w);
    o[4] = (short)f2bf(b.x); o[5] = (short)f2bf(b.y);
    o[6] = (short)f2bf(b.z); o[7] = (short)f2bf(b.w);
    *reinterpret_cast<s8v*>(dst + (size_t)i * 8) = o;
}

// ---------------------------------------------------------------------------
// m97-structure GEMM-BT (byte-identical R21/R22): C = A[M,768] @ Bm[N,768]^T.
// BM=BN=128, BK=64. 4 waves, 32KB swizzled single-buffer LDS, XCD-bijective
// block swizzle. EPI==0: q/k scatter + V packed ushort4. EPI==1: +bias fp32.
// ---------------------------------------------------------------------------
template <int EPI>
__global__ __launch_bounds__(256) void gemm_m97(
    const uint16_t* __restrict__ A, const uint16_t* __restrict__ Bm,
    uint16_t* __restrict__ qb, uint16_t* __restrict__ kb, uint16_t* __restrict__ vb,
    const float* __restrict__ bias, float* __restrict__ Cout, int GN)
{
    constexpr int K  = 768;
    constexpr int NT = K / 64;               // 12 K-steps

    __shared__ uint16_t Al[128 * 64];        // 16 KB
    __shared__ uint16_t Bl[128 * 64];        // 16 KB

    const int tid  = threadIdx.x;
    const int wave = tid >> 6, lane = tid & 63;
    const int quad = lane >> 4, l16 = lane & 15;
    const int wM = wave >> 1, wN = wave & 1;

    // T1: XCD-bijective swizzle (gridDim.x % 8 == 0 for both call sites)
    const int nwg = (int)gridDim.x;
    const int wg  = ((int)blockIdx.x & 7) * (nwg >> 3) + ((int)blockIdx.x >> 3);
    const int bM = wg / GN, bN = wg - bM * GN;

    const uint16_t* Ag = A  + (size_t)bM * 128 * K;
    const uint16_t* Bg = Bm + (size_t)bN * 128 * K;

    f4v acc[4][4];
#pragma unroll
    for (int i = 0; i < 4; i++)
#pragma unroll
        for (int j = 0; j < 4; j++) { f4v z = {0.f, 0.f, 0.f, 0.f}; acc[i][j] = z; }

    for (int t = 0; t < NT; ++t) {
        __syncthreads();
        // chunk ch: row r=ch>>3; phys chunk ch&7 holds logical lc=(ch&7)^(r&7)
#pragma unroll
        for (int u = 0; u < 4; ++u) {
            const int ch = tid + u * 256;
            const int r  = ch >> 3, lc = (ch & 7) ^ (r & 7);
            cp16(Ag + (size_t)r * K + t * 64 + lc * 8, &Al[ch * 8]);
        }
#pragma unroll
        for (int u = 0; u < 4; ++u) {
            const int ch = tid + u * 256;
            const int r  = ch >> 3, lc = (ch & 7) ^ (r & 7);
            cp16(Bg + (size_t)r * K + t * 64 + lc * 8, &Bl[ch * 8]);
        }
        __syncthreads();

        s8v af[4][2], bq[4][2];
#pragma unroll
        for (int x = 0; x < 4; ++x) {
            const int ra = wM * 64 + x * 16 + l16;
            const int rb = wN * 64 + x * 16 + l16;
#pragma unroll
            for (int kk = 0; kk < 2; ++kk) {
                const int pa = (kk * 4 + quad) ^ (ra & 7);
                const int pb = (kk * 4 + quad) ^ (rb & 7);
                af[x][kk] = *reinterpret_cast<const s8v*>(&Al[ra * 64 + pa * 8]);
                bq[x][kk] = *reinterpret_cast<const s8v*>(&Bl[rb * 64 + pb * 8]);
            }
        }
#pragma unroll
        for (int kk = 0; kk < 2; ++kk)
#pragma unroll
            for (int tm = 0; tm < 4; ++tm)
#pragma unroll
                for (int tn = 0; tn < 4; ++tn)
                    acc[tm][tn] = __builtin_amdgcn_mfma_f32_16x16x32_bf16(
                        af[tm][kk], bq[tn][kk], acc[tm][tn], 0, 0, 0);
    }

    // epilogue (identical scatter logic; BN=128)
#pragma unroll
    for (int tm = 0; tm < 4; tm++) {
#pragma unroll
        for (int tn = 0; tn < 4; tn++) {
            const int col = bN * 128 + wN * 64 + tn * 16 + l16;
            if (EPI == 0) {
                const int three = col / 768;          // block-uniform (128 | 768)
                const int rem   = col - three * 768;
                const int h = rem >> 6, d = rem & 63;
                const int n0 = bM * 128 + wM * 64 + tm * 16 + quad * 4;
                const int b = n0 >> 10, n = n0 & 1023;   // n0%4==0: no b crossing
                if (three == 2) {
                    // V: 4 regs = 4 consecutive tokens at fixed vdim -> ushort4
                    ushort4 pk;
                    pk.x = f2bf(acc[tm][tn][0]);
                    pk.y = f2bf(acc[tm][tn][1]);
                    pk.z = f2bf(acc[tm][tn][2]);
                    pk.w = f2bf(acc[tm][tn][3]);
                    *reinterpret_cast<ushort4*>(
                        &vb[((size_t)((b * 12 + h) * 64 + d)) * 1024 + n]) = pk;
                } else {
                    uint16_t* dst = (three == 0) ? qb : kb;
#pragma unroll
                    for (int reg = 0; reg < 4; reg++)
                        dst[((size_t)((b * 12 + h) * 1024 + n + reg)) * 64 + d] =
                            f2bf(acc[tm][tn][reg]);
                }
            } else {
#pragma unroll
                for (int reg = 0; reg < 4; reg++) {
                    const int row = bM * 128 + wM * 64 + tm * 16 + quad * 4 + reg;
                    Cout[(size_t)row * 768 + col] = acc[tm][tn][reg] + bias[col];
                }
            }
        }
    }
}

// ---------------------------------------------------------------------------
// Fused quad2 attention (R22 2-wave sequential + stride-88 Pl).
// Grid: x=96 (b*12+h, fast -> same-bh blocks on one XCD), y=8 (128-row
// q-tile). 2 waves; wave owns 64 q-rows as 4 subtiles. Per m-tile: swizzled
// cp16 stage of K[m][d], V^T[d][m]; hoist K/V frags (XOR-swizzled reads);
// S^T = K@Q^T -> t=(s/8+5)^2 -> packed b64 P writes (stride-88 Pl: 12*l16
// mod 32 has period 8 -> free 2-way, vs stride-80's 4-way) -> PV +
// ones-MFMA rowsum. Final O = U/rowsum.
// ---------------------------------------------------------------------------
__global__ __launch_bounds__(128, 2) void attn_quad(
    const uint16_t* __restrict__ Q, const uint16_t* __restrict__ K,
    const uint16_t* __restrict__ VT, uint16_t* __restrict__ O)
{
    const int bh = blockIdx.x;      // 0..95  (fast dim: same-bh -> same XCD)
    const int qt = blockIdx.y;      // 0..7
    const int b = bh / 12, h = bh - (bh / 12) * 12;
    const uint16_t* Qp = Q  + (size_t)bh * 65536;
    const uint16_t* Kp = K  + (size_t)bh * 65536;
    const uint16_t* Vp = VT + (size_t)bh * 65536;   // [d=64][n=1024]

    const int tid  = threadIdx.x;
    const int wave = tid >> 6, lane = tid & 63;
    const int quad = lane >> 4, l16 = lane & 15;

    __shared__ uint16_t Kl[64 * 64];     // [key][d], chunk-swizzled
    __shared__ uint16_t Vl[64 * 64];     // [d][m],  chunk-swizzled
    __shared__ uint16_t Pl[2][16][88];   // per-wave [qrow][m], stride 88

    // Q fragments (one-time, direct global)
    s8v qf[4][2];
#pragma unroll
    for (int s = 0; s < 4; s++) {
        const uint16_t* qp = Qp + (size_t)(qt * 128 + wave * 64 + s * 16 + l16) * 64 + quad * 8;
        qf[s][0] = *reinterpret_cast<const s8v*>(qp);
        qf[s][1] = *reinterpret_cast<const s8v*>(qp + 32);
    }

    s8v ones;
#pragma unroll
    for (int i = 0; i < 8; i++) ones[i] = (short)0x3F80;   // bf16 1.0

    f4v U[4][4], U5[4];
#pragma unroll
    for (int s = 0; s < 4; s++) {
        f4v z = {0.f, 0.f, 0.f, 0.f};
        U5[s] = z;
#pragma unroll
        for (int c = 0; c < 4; c++) U[s][c] = z;
    }

    for (int mt = 0; mt < 16; mt++) {
        __syncthreads();
        // swizzled staging: physical chunk pc of row holds logical pc^(row&7)
#pragma unroll
        for (int r = 0; r < 4; r++) {
            const int e   = (tid + r * 128) * 8;
            const int row = e >> 6;                       // key for K, d for V
            const int cl  = ((e >> 3) & 7) ^ (row & 7);   // logical chunk fetched
            cp16(Kp + (size_t)mt * 4096 + (size_t)row * 64 + cl * 8, &Kl[e]);
            cp16(Vp + (size_t)row * 1024 + mt * 64 + cl * 8, &Vl[e]);
        }
        __syncthreads();

        // hoist K/V fragments (reused by all 4 subtiles); XOR-swizzled reads
        s8v kf[4][2], vf[4][2];
#pragma unroll
        for (int c = 0; c < 4; c++) {
            const int rr = c * 16 + l16;
#pragma unroll
            for (int kk = 0; kk < 2; kk++) {
                const int pc = (kk * 4 + quad) ^ (rr & 7);
                kf[c][kk] = *reinterpret_cast<const s8v*>(&Kl[rr * 64 + (pc << 3)]);
                vf[c][kk] = *reinterpret_cast<const s8v*>(&Vl[rr * 64 + (pc << 3)]);
            }
        }

#pragma unroll
        for (int s = 0; s < 4; s++) {
            // S^T = K @ Q^T : C col=l16=qrow, row=quad*4+reg = m (in cm tile)
            f4v st[4];
#pragma unroll
            for (int cm = 0; cm < 4; cm++) {
                f4v z = {0.f, 0.f, 0.f, 0.f};
                z = __builtin_amdgcn_mfma_f32_16x16x32_bf16(kf[cm][0], qf[s][0], z, 0, 0, 0);
                z = __builtin_amdgcn_mfma_f32_16x16x32_bf16(kf[cm][1], qf[s][1], z, 0, 0, 0);
                st[cm] = z;
            }
            // t = (s*0.125+5)^2 -> packed b64 write: Pl[l16][cm*16+quad*4 ..+3]
#pragma unroll
            for (int cm = 0; cm < 4; cm++) {
                float t0 = st[cm][0] * 0.125f + 5.0f; t0 *= t0;
                float t1 = st[cm][1] * 0.125f + 5.0f; t1 *= t1;
                float t2 = st[cm][2] * 0.125f + 5.0f; t2 *= t2;
                float t3 = st[cm][3] * 0.125f + 5.0f; t3 *= t3;
                uint2 pk; pk.x = pack2bf(t0, t1); pk.y = pack2bf(t2, t3);
                *reinterpret_cast<uint2*>(&Pl[wave][l16][cm * 16 + quad * 4]) = pk;
            }
            // U += P @ V ; rowsum via ones-MFMA (same-wave DS in-order)
#pragma unroll
            for (int kc = 0; kc < 2; kc++) {
                s8v pf = *reinterpret_cast<const s8v*>(&Pl[wave][l16][kc * 32 + quad * 8]);
                U5[s] = __builtin_amdgcn_mfma_f32_16x16x32_bf16(pf, ones, U5[s], 0, 0, 0);
#pragma unroll
                for (int cd = 0; cd < 4; cd++)
                    U[s][cd] = __builtin_amdgcn_mfma_f32_16x16x32_bf16(pf, vf[cd][kc], U[s][cd], 0, 0, 0);
            }
        }
    }

    // epilogue: O[b, n, h*64+d] = U / rowsum (bf16 intermediate for proj GEMM)
#pragma unroll
    for (int s = 0; s < 4; s++) {
        float inv[4];
#pragma unroll
        for (int reg = 0; reg < 4; reg++) inv[reg] = 1.0f / U5[s][reg];
#pragma unroll
        for (int cd = 0; cd < 4; cd++) {
#pragma unroll
            for (int reg = 0; reg < 4; reg++) {
                const int n = qt * 128 + wave * 64 + s * 16 + quad * 4 + reg;
                const int d = cd * 16 + l16;
                O[((size_t)(b * 1024 + n)) * 768 + h * 64 + d] = f2bf(U[s][cd][reg] * inv[reg]);
            }
        }
    }
}

// ---------------------------------------------------------------------------
extern "C" void kernel_launch(void* const* d_in, const int* in_sizes, int n_in,
                              void* d_out, int out_size, void* d_ws, size_t ws_size,
                              hipStream_t stream)
{
    const float* x      = (const float*)d_in[0];   // [8,1024,768]
    const float* qkv_w  = (const float*)d_in[1];   // [2304,768]
    const float* proj_w = (const float*)d_in[2];   // [768,768]
    const float* proj_b = (const float*)d_in[3];   // [768]
    float* out = (float*)d_out;                    // [8,1024,768] fp32

    const size_t NEL = (size_t)8 * 1024 * 768;     // 6291456
    uint16_t* xb  = (uint16_t*)d_ws;               // bf16 x
    uint16_t* qwb = xb  + NEL;                     // bf16 qkv_w (1769472)
    uint16_t* pwb = qwb + 1769472;                 // bf16 proj_w (589824)
    uint16_t* qb  = pwb + 589824;                  // bf16 [B,H,N,64]
    uint16_t* kb  = qb  + NEL;                     // bf16 [B,H,N,64]
    uint16_t* vb  = kb  + NEL;                     // bf16 [B,H,64,N] (transposed)
    uint16_t* ao  = vb  + NEL;                     // bf16 attn out [8192,768]

    cvt_all<<<4224, 256, 0, stream>>>(x, qkv_w, proj_w, xb);

    // QKV: [8192,768] @ [2304,768]^T -> q/k scatter + V packed ushort4
    gemm_m97<0><<<1152, 256, 0, stream>>>(xb, qwb, qb, kb, vb, nullptr, nullptr, 18);
    // fused quad2 attention -> ao [8192,768] bf16
    // bh fast (x=96): same-bh blocks on one XCD (FETCH 104.5->19.4MB, R22)
    attn_quad<<<dim3(96, 8), 128, 0, stream>>>(qb, kb, vb, ao);
    // proj: [8192,768] @ [768,768]^T + bias -> fp32 out
    gemm_m97<1><<<384, 256, 0, stream>>>(ao, pwb, nullptr, nullptr, nullptr, proj_b, out, 6);
}